// Round 11
// baseline (142.395 us; speedup 1.0000x reference)
//
#include <hip/hip_runtime.h>
#include <hip/hip_fp16.h>
#include <hip/hip_cooperative_groups.h>

namespace cg = cooperative_groups;

#define N_REL 201   // NUM_RELS + 1 (PAD row 200 is all-zero)
#define N_TGT 200   // target_rels < 200
#define SEM 32      // SEM_DIM
#define KNEI 20     // K neighbors
#define PSTRIDE 40  // halfs per P row (80 B -> uniform 8-class bank phases)

typedef float floatx4 __attribute__((ext_vector_type(4)));

// Workspace: [0,80400) __half St[200][201]; [80400,+32160) __half P[402][40]
#define ST_ELEMS (N_TGT * N_REL)                  // 40200
#define BUILD_TOTAL (ST_ELEMS + 2 * N_REL * SEM)  // 53064
#define ST_BYTES 80400
#define P_HALFS (2 * N_REL * PSTRIDE)             // 16080
#define P_U4 (P_HALFS * 2 / 16)                   // 2010

#define NBLK 512
#define NTHR 512
#define CHUNK 64   // nodes per block-iteration (NTHR/8)

// ---------------------------------------------------------------------------
// ONE cooperative kernel: phase A builds St/P (flat, one dot per thread);
// chunk-0 input prefetch BEFORE grid.sync (overlaps build); then 2 grid-stride
// fuse iterations with P staged once per block and it1 inputs prefetched
// during it0 compute.  mode: 0 = cooperative all-in-one; 1 = build only;
// 2 = fuse only (fallback if cooperative launch unavailable).
// ---------------------------------------------------------------------------
__global__ __launch_bounds__(NTHR, 4) void fused_all(
    const int* __restrict__ out_nei, const int* __restrict__ in_nei,
    const int* __restrict__ target, const float* __restrict__ feat,
    const float* __restrict__ rel_emb, const float* __restrict__ w,
    const float* __restrict__ bias,
    __half* __restrict__ St, __half* __restrict__ P,
    float* __restrict__ out, int n_nodes, int mode)
{
  __shared__ __align__(16) __half P_l[P_HALFS];   // 32160 B
  const int t = threadIdx.x;
  const int b = blockIdx.x;

  // ---- phase A: build tables ----
  if (mode != 2) {
    const int g = b * NTHR + t;
    if (g < ST_ELEMS) {
      const int j = g / N_REL;            // target row
      const int i = g - j * N_REL;        // idx col
      const floatx4* ei = (const floatx4*)(rel_emb + i * 64);
      const floatx4* ej = (const floatx4*)(rel_emb + j * 64);
      float acc = 0.f;
#pragma unroll
      for (int d = 0; d < 16; ++d) {
        const floatx4 a = ei[d], c = ej[d];
        acc = fmaf(a.x, c.x, acc); acc = fmaf(a.y, c.y, acc);
        acc = fmaf(a.z, c.z, acc); acc = fmaf(a.w, c.w, acc);
      }
      St[g] = __float2half(acc);          // g == j*201 + i
    } else if (g < BUILD_TOTAL) {
      const int g2 = g - ST_ELEMS;
      const int r = g2 >> 5;              // 0..401 (dir*201 + i)
      const int c = g2 & 31;
      const int i = (r < N_REL) ? r : (r - N_REL);
      const int woff = (r < N_REL) ? 0 : 64;
      const floatx4* ei = (const floatx4*)(rel_emb + i * 64);
      const floatx4* wc = (const floatx4*)(w + c * 128 + woff);
      float acc = 0.5f * bias[c];
#pragma unroll
      for (int d = 0; d < 16; ++d) {
        const floatx4 a = ei[d], cw = wc[d];
        acc = fmaf(a.x, cw.x, acc); acc = fmaf(a.y, cw.y, acc);
        acc = fmaf(a.z, cw.z, acc); acc = fmaf(a.w, cw.w, acc);
      }
      P[r * PSTRIDE + c] = __float2half(acc);
    }
    if (mode == 1) return;
  }

  const int sub = t & 7;
  const int dir = sub >> 2;   // 0 = out, 1 = in
  const int q = sub & 3;      // 8-dim slice / k-phase
  const int lslot = t >> 3;
  const int* __restrict__ nei = dir ? in_nei : out_nei;

  // ---- prefetch chunk-0 inputs (table-independent; overlaps build+sync) ----
  int curN = b * CHUNK + lslot;
  bool curA = (curN < n_nodes);
  int curTgt = 0; int cIdx[5] = {0, 0, 0, 0, 0};
  floatx4 cF0, cF1;
  if (curA) {
    curTgt = target[curN];
#pragma unroll
    for (int i = 0; i < 5; ++i) cIdx[i] = nei[(size_t)curN * KNEI + 4 * i + q];
    if (dir == 0) {
      const floatx4* fr = (const floatx4*)(feat + (size_t)curN * SEM + q * 8);
      cF0 = __builtin_nontemporal_load(fr);
      cF1 = __builtin_nontemporal_load(fr + 1);
    }
  }

  if (mode == 0) {
    __threadfence();            // make St/P device-visible
    cg::this_grid().sync();
  }

  // ---- stage P into LDS once per block ----
  {
    const uint4* p4 = (const uint4*)P;
    uint4* pl = (uint4*)P_l;
    for (int e = t; e < P_U4; e += NTHR) pl[e] = p4[e];
  }
  __syncthreads();

#pragma unroll
  for (int it = 0; it < 2; ++it) {
    // S gathers for current chunk (St row curTgt; L1/L2-hot)
    float ev[5];
    if (curA) {
      const __half* __restrict__ srow = St + (size_t)curTgt * N_REL;
#pragma unroll
      for (int i = 0; i < 5; ++i) ev[i] = __half2float(srow[cIdx[i]]);
    }
    // prefetch next chunk while gathers are in flight
    int nxtN = 0, nxtTgt = 0; bool nxtA = false;
    int nIdx[5] = {0, 0, 0, 0, 0};
    floatx4 nF0, nF1;
    if (it == 0) {
      nxtN = (b + NBLK) * CHUNK + lslot;
      nxtA = (nxtN < n_nodes);
      if (nxtA) {
        nxtTgt = target[nxtN];
#pragma unroll
        for (int i = 0; i < 5; ++i) nIdx[i] = nei[(size_t)nxtN * KNEI + 4 * i + q];
        if (dir == 0) {
          const floatx4* fr = (const floatx4*)(feat + (size_t)nxtN * SEM + q * 8);
          nF0 = __builtin_nontemporal_load(fr);
          nF1 = __builtin_nontemporal_load(fr + 1);
        }
      }
    }

    if (curA) {
      // softmax WITH max-subtraction (self-neighbor scores reach ~||emb||^2
      // ~ 100 -> expf overflows without it; learned in r10's NaN).
      float mx = ev[0];
#pragma unroll
      for (int i = 1; i < 5; ++i) mx = fmaxf(mx, ev[i]);
      mx = fmaxf(mx, __shfl_xor(mx, 1, 64));
      mx = fmaxf(mx, __shfl_xor(mx, 2, 64));
      float e5[5]; float s = 0.f;
#pragma unroll
      for (int i = 0; i < 5; ++i) { e5[i] = __expf(ev[i] - mx); s += e5[i]; }
      s += __shfl_xor(s, 1, 64);
      s += __shfl_xor(s, 2, 64);
      const float inv = __fdividef(1.f, s);

      unsigned int pk[20];
#pragma unroll
      for (int i = 0; i < 5; ++i) {
        const __half hw = __float2half(e5[i] * inv);
        pk[i] = ((unsigned int)cIdx[i] << 16) | (unsigned int)__half_as_ushort(hw);
      }
#pragma unroll
      for (int i = 0; i < 5; ++i) pk[5 + i] = __shfl_xor(pk[i], 1, 64);
#pragma unroll
      for (int i = 0; i < 10; ++i) pk[10 + i] = __shfl_xor(pk[i], 2, 64);

      __half2 acc[4];
#pragma unroll
      for (int m = 0; m < 4; ++m) acc[m] = __float2half2_rn(0.f);
      const int dbase = dir * (N_REL * PSTRIDE) + q * 8;
#pragma unroll
      for (int i = 0; i < 20; ++i) {
        const int idx = (int)(pk[i] >> 16);
        const unsigned int lo = pk[i] & 0xFFFFu;
        const unsigned int dd = lo | (lo << 16);
        const __half2 a2 = *(const __half2*)&dd;
        const uint4 qv = *(const uint4*)&P_l[dbase + idx * PSTRIDE];
        acc[0] = __hfma2(a2, *(const __half2*)&qv.x, acc[0]);
        acc[1] = __hfma2(a2, *(const __half2*)&qv.y, acc[1]);
        acc[2] = __hfma2(a2, *(const __half2*)&qv.z, acc[2]);
        acc[3] = __hfma2(a2, *(const __half2*)&qv.w, acc[3]);
      }
#pragma unroll
      for (int m = 0; m < 4; ++m) {
        const unsigned int u = *(const unsigned int*)&acc[m];
        const unsigned int v = __shfl_xor(u, 4, 64);
        acc[m] = __hadd2(acc[m], *(const __half2*)&v);
      }

      float* orow = out + (size_t)curN * 64 + sub * 8;
      if (dir == 0) {
        __builtin_nontemporal_store(cF0, (floatx4*)orow);
        __builtin_nontemporal_store(cF1, (floatx4*)orow + 1);
      } else {
        float tv[8];
#pragma unroll
        for (int m = 0; m < 4; ++m) {
          tv[2 * m]     = __low2float(acc[m]);
          tv[2 * m + 1] = __high2float(acc[m]);
        }
        floatx4 s0, s1;
        s0.x = __fdividef(1.f, 1.f + __expf(-tv[0]));
        s0.y = __fdividef(1.f, 1.f + __expf(-tv[1]));
        s0.z = __fdividef(1.f, 1.f + __expf(-tv[2]));
        s0.w = __fdividef(1.f, 1.f + __expf(-tv[3]));
        s1.x = __fdividef(1.f, 1.f + __expf(-tv[4]));
        s1.y = __fdividef(1.f, 1.f + __expf(-tv[5]));
        s1.z = __fdividef(1.f, 1.f + __expf(-tv[6]));
        s1.w = __fdividef(1.f, 1.f + __expf(-tv[7]));
        __builtin_nontemporal_store(s0, (floatx4*)orow);
        __builtin_nontemporal_store(s1, (floatx4*)orow + 1);
      }
    }
    // rotate prefetched state
    curN = nxtN; curTgt = nxtTgt; curA = nxtA;
#pragma unroll
    for (int i = 0; i < 5; ++i) cIdx[i] = nIdx[i];
    cF0 = nF0; cF1 = nF1;
  }
}

extern "C" void kernel_launch(void* const* d_in, const int* in_sizes, int n_in,
                              void* d_out, int out_size, void* d_ws, size_t ws_size,
                              hipStream_t stream) {
  const int* out_nei   = (const int*)d_in[0];
  const int* in_nei    = (const int*)d_in[1];
  const int* target    = (const int*)d_in[2];
  const float* feat    = (const float*)d_in[3];
  const float* rel_emb = (const float*)d_in[4];
  const float* w       = (const float*)d_in[5];
  const float* bias    = (const float*)d_in[6];
  float* out = (float*)d_out;
  int n_nodes = in_sizes[2];

  __half* St = (__half*)d_ws;
  __half* P  = (__half*)((char*)d_ws + ST_BYTES);

  int mode0 = 0;
  void* args[] = {&out_nei, &in_nei, &target, &feat, &rel_emb, &w, &bias,
                  &St, &P, &out, &n_nodes, &mode0};
  hipError_t err = hipLaunchCooperativeKernel((void*)fused_all, dim3(NBLK),
                                              dim3(NTHR), args, 0, stream);
  if (err != hipSuccess) {
    // Fallback: split launches (build fully completes, then fuse).
    fused_all<<<NBLK, NTHR, 0, stream>>>(out_nei, in_nei, target, feat,
                                         rel_emb, w, bias, St, P, out,
                                         n_nodes, 1);
    fused_all<<<NBLK, NTHR, 0, stream>>>(out_nei, in_nei, target, feat,
                                         rel_emb, w, bias, St, P, out,
                                         n_nodes, 2);
  }
}

// Round 12
// 21.269 us; speedup vs baseline: 6.6951x; 6.6951x over previous
//
#include <hip/hip_runtime.h>
#include <hip/hip_fp16.h>

#define N_REL 201   // NUM_RELS + 1 (PAD row 200 is all-zero)
#define N_TGT 200   // target_rels < 200
#define SEM 32      // SEM_DIM
#define KNEI 20     // K neighbors
#define PSTRIDE 40  // halfs per P row (80 B -> uniform 8-class bank phases)

typedef float floatx4 __attribute__((ext_vector_type(4)));

// Workspace: [0,80400) __half St[200][201]; [80400,+32160) __half P[402][40]
#define ST_BYTES 80400                 // 16-aligned (16*5025)
#define P_HALFS (2 * N_REL * PSTRIDE)  // 16080
#define P_U4 (P_HALFS * 2 / 16)        // 2010

#define EMB_STRIDE 68   // floats/row: 16B-aligned, dword-stride 17 (odd)
#define WL_STRIDE 132   // floats/row: 16B-aligned, dword-stride 33 (odd)

// ---------------------------------------------------------------------------
// Kernel 1 (vectorized, from r7): St[j][i] = emb[i]·emb[j] (fp16);
// P[dir*201+i][c] = emb[i]·W_dir_c + bias[c]/2 (fp16).
// ---------------------------------------------------------------------------
__global__ __launch_bounds__(256) void build_tables_kernel(
    const float* __restrict__ rel_emb,   // [201][64]
    const float* __restrict__ w,         // [32][128]
    const float* __restrict__ bias,      // [32]
    __half* __restrict__ St,             // [200][201] transposed
    __half* __restrict__ P)              // [402][PSTRIDE]
{
  __shared__ __align__(16) float embL[N_REL * EMB_STRIDE];
  __shared__ __align__(16) float wL[SEM * WL_STRIDE];
  const int t = threadIdx.x;
  for (int e = t; e < N_REL * 16; e += 256) {
    const int r = e >> 4, s = e & 15;
    *(float4*)&embL[r * EMB_STRIDE + s * 4] = ((const float4*)rel_emb)[e];
  }
  for (int e = t; e < SEM * 32; e += 256) {
    const int r = e >> 5, s = e & 31;
    *(float4*)&wL[r * WL_STRIDE + s * 4] = ((const float4*)w)[e];
  }
  __syncthreads();

  const int i = blockIdx.x;  // 0..200 (idx dimension)
  const float4* __restrict__ ri = (const float4*)&embL[i * EMB_STRIDE];
  for (int jj = t; jj < N_TGT; jj += 256) {
    const float4* __restrict__ rj = (const float4*)&embL[jj * EMB_STRIDE];
    float acc = 0.f;
#pragma unroll
    for (int d = 0; d < 16; ++d) {
      const float4 a = ri[d], b = rj[d];
      acc = fmaf(a.x, b.x, acc);
      acc = fmaf(a.y, b.y, acc);
      acc = fmaf(a.z, b.z, acc);
      acc = fmaf(a.w, b.w, acc);
    }
    St[jj * N_REL + i] = __float2half(acc);
  }
  if (t < 64) {
    const int hh = t >> 5, jj = t & 31;
    const float4* __restrict__ rw = (const float4*)&wL[jj * WL_STRIDE + hh * 64];
    float acc = 0.5f * bias[jj];
#pragma unroll
    for (int d = 0; d < 16; ++d) {
      const float4 a = ri[d], b = rw[d];
      acc = fmaf(a.x, b.x, acc);
      acc = fmaf(a.y, b.y, acc);
      acc = fmaf(a.z, b.z, acc);
      acc = fmaf(a.w, b.w, acc);
    }
    P[(hh * N_REL + i) * PSTRIDE + jj] = __float2half(acc);
  }
}

// ---------------------------------------------------------------------------
// Kernel 2: 8 LANES PER NODE, 2-NODE-DEEP per thread. 256-thr blocks,
// 64 nodes/block (32 slots x 2), 782 blocks (same balance as r7).
// Pipeline: issue A+B input loads -> stage P -> A+B S-gathers -> compute A
// -> compute B. Lane q owns k in {4q..4q+3, 16+q} (uint4+dword idx loads).
// ---------------------------------------------------------------------------
__global__ __launch_bounds__(256, 4) void fuse_kernel(
    const int* __restrict__ out_nei, const int* __restrict__ in_nei,
    const int* __restrict__ target, const float* __restrict__ feat,
    const __half* __restrict__ St, const __half* __restrict__ Pg,
    float* __restrict__ out, int n_nodes)
{
  __shared__ __align__(16) __half P_l[P_HALFS];    // 32160 B
  const int t = threadIdx.x;
  const int slot = t >> 3;     // 0..31
  const int sub = t & 7;
  const int dir = sub >> 2;    // 0 = out, 1 = in
  const int q = sub & 3;       // 8-dim slice / k-chunk
  const int nA = blockIdx.x * 64 + slot;
  const int nB = nA + 32;
  const bool aA = (nA < n_nodes);
  const bool aB = (nB < n_nodes);
  const int* __restrict__ nei = dir ? in_nei : out_nei;

  // ---- phase 1: issue BOTH nodes' input loads (deep MLP) ----
  int tgtA = 0, tgtB = 0, exA = 0, exB = 0;
  uint4 c4A = {0, 0, 0, 0}, c4B = {0, 0, 0, 0};
  floatx4 fA0, fA1, fB0, fB1;
  if (aA) {
    tgtA = target[nA];
    c4A = *(const uint4*)(nei + (size_t)nA * KNEI + 4 * q);
    exA = nei[(size_t)nA * KNEI + 16 + q];
    if (dir == 0) {
      const floatx4* fr = (const floatx4*)(feat + (size_t)nA * SEM + q * 8);
      fA0 = fr[0]; fA1 = fr[1];
    }
  }
  if (aB) {
    tgtB = target[nB];
    c4B = *(const uint4*)(nei + (size_t)nB * KNEI + 4 * q);
    exB = nei[(size_t)nB * KNEI + 16 + q];
    if (dir == 0) {
      const floatx4* fr = (const floatx4*)(feat + (size_t)nB * SEM + q * 8);
      fB0 = fr[0]; fB1 = fr[1];
    }
  }

  // ---- phase 2: stage P into LDS (covers phase-1 latency) ----
  {
    const uint4* p4 = (const uint4*)Pg;
    uint4* pl = (uint4*)P_l;
    for (int e = t; e < P_U4; e += 256) pl[e] = p4[e];
  }
  __syncthreads();

  // ---- phase 3: S gathers for both nodes (two independent streams) ----
  float evA[5], evB[5];
  if (aA) {
    const __half* __restrict__ sr = St + (size_t)tgtA * N_REL;
    evA[0] = __half2float(sr[c4A.x]);
    evA[1] = __half2float(sr[c4A.y]);
    evA[2] = __half2float(sr[c4A.z]);
    evA[3] = __half2float(sr[c4A.w]);
    evA[4] = __half2float(sr[exA]);
  }
  if (aB) {
    const __half* __restrict__ sr = St + (size_t)tgtB * N_REL;
    evB[0] = __half2float(sr[c4B.x]);
    evB[1] = __half2float(sr[c4B.y]);
    evB[2] = __half2float(sr[c4B.z]);
    evB[3] = __half2float(sr[c4B.w]);
    evB[4] = __half2float(sr[exB]);
  }

  // ---- phase 4: process both nodes ----
#pragma unroll
  for (int pass = 0; pass < 2; ++pass) {
    const bool act = pass ? aB : aA;
    if (!act) continue;
    const int n = pass ? nB : nA;
    float ev[5];
    int i0, i1, i2, i3, i4;
    if (pass == 0) {
      ev[0] = evA[0]; ev[1] = evA[1]; ev[2] = evA[2]; ev[3] = evA[3]; ev[4] = evA[4];
      i0 = (int)c4A.x; i1 = (int)c4A.y; i2 = (int)c4A.z; i3 = (int)c4A.w; i4 = exA;
    } else {
      ev[0] = evB[0]; ev[1] = evB[1]; ev[2] = evB[2]; ev[3] = evB[3]; ev[4] = evB[4];
      i0 = (int)c4B.x; i1 = (int)c4B.y; i2 = (int)c4B.z; i3 = (int)c4B.w; i4 = exB;
    }

    // softmax with max-subtraction (self-neighbor scores ~||emb||^2 ~ 100)
    float mx = fmaxf(fmaxf(fmaxf(ev[0], ev[1]), fmaxf(ev[2], ev[3])), ev[4]);
    mx = fmaxf(mx, __shfl_xor(mx, 1, 64));
    mx = fmaxf(mx, __shfl_xor(mx, 2, 64));
    float e5[5], s = 0.f;
#pragma unroll
    for (int i = 0; i < 5; ++i) { e5[i] = __expf(ev[i] - mx); s += e5[i]; }
    s += __shfl_xor(s, 1, 64);
    s += __shfl_xor(s, 2, 64);
    const float inv = __fdividef(1.f, s);

    // pack {idx | w_fp16}; all-gather within the dir quad (order-invariant)
    unsigned int pk[20];
    const int ia[5] = {i0, i1, i2, i3, i4};
#pragma unroll
    for (int i = 0; i < 5; ++i) {
      const __half hw = __float2half(e5[i] * inv);
      pk[i] = ((unsigned int)ia[i] << 16) | (unsigned int)__half_as_ushort(hw);
    }
#pragma unroll
    for (int i = 0; i < 5; ++i) pk[5 + i] = __shfl_xor(pk[i], 1, 64);
#pragma unroll
    for (int i = 0; i < 10; ++i) pk[10 + i] = __shfl_xor(pk[i], 2, 64);

    // aggregate 20 rows, own 8-dim slice (1 b128 per row)
    __half2 acc[4];
#pragma unroll
    for (int m = 0; m < 4; ++m) acc[m] = __float2half2_rn(0.f);
    const int dbase = dir * (N_REL * PSTRIDE) + q * 8;
#pragma unroll
    for (int i = 0; i < 20; ++i) {
      const int idx = (int)(pk[i] >> 16);
      const unsigned int lo = pk[i] & 0xFFFFu;
      const unsigned int dd = lo | (lo << 16);
      const __half2 a2 = *(const __half2*)&dd;
      const uint4 qv = *(const uint4*)&P_l[dbase + idx * PSTRIDE];
      acc[0] = __hfma2(a2, *(const __half2*)&qv.x, acc[0]);
      acc[1] = __hfma2(a2, *(const __half2*)&qv.y, acc[1]);
      acc[2] = __hfma2(a2, *(const __half2*)&qv.z, acc[2]);
      acc[3] = __hfma2(a2, *(const __half2*)&qv.w, acc[3]);
    }

    // combine directions: partner lane = lane ^ 4
#pragma unroll
    for (int m = 0; m < 4; ++m) {
      const unsigned int u = *(const unsigned int*)&acc[m];
      const unsigned int v = __shfl_xor(u, 4, 64);
      acc[m] = __hadd2(acc[m], *(const __half2*)&v);
    }

    // write: lanes 0-3 -> feat slice, lanes 4-7 -> sigmoid slice (NT stores)
    float* orow = out + (size_t)n * 64 + sub * 8;
    if (dir == 0) {
      const floatx4 f0 = pass ? fB0 : fA0;
      const floatx4 f1 = pass ? fB1 : fA1;
      __builtin_nontemporal_store(f0, (floatx4*)orow);
      __builtin_nontemporal_store(f1, (floatx4*)orow + 1);
    } else {
      float tv[8];
#pragma unroll
      for (int m = 0; m < 4; ++m) {
        tv[2 * m]     = __low2float(acc[m]);
        tv[2 * m + 1] = __high2float(acc[m]);
      }
      floatx4 s0, s1;
      s0.x = __fdividef(1.f, 1.f + __expf(-tv[0]));
      s0.y = __fdividef(1.f, 1.f + __expf(-tv[1]));
      s0.z = __fdividef(1.f, 1.f + __expf(-tv[2]));
      s0.w = __fdividef(1.f, 1.f + __expf(-tv[3]));
      s1.x = __fdividef(1.f, 1.f + __expf(-tv[4]));
      s1.y = __fdividef(1.f, 1.f + __expf(-tv[5]));
      s1.z = __fdividef(1.f, 1.f + __expf(-tv[6]));
      s1.w = __fdividef(1.f, 1.f + __expf(-tv[7]));
      __builtin_nontemporal_store(s0, (floatx4*)orow);
      __builtin_nontemporal_store(s1, (floatx4*)orow + 1);
    }
  }
}

extern "C" void kernel_launch(void* const* d_in, const int* in_sizes, int n_in,
                              void* d_out, int out_size, void* d_ws, size_t ws_size,
                              hipStream_t stream) {
  const int* out_nei   = (const int*)d_in[0];
  const int* in_nei    = (const int*)d_in[1];
  const int* target    = (const int*)d_in[2];
  const float* feat    = (const float*)d_in[3];
  const float* rel_emb = (const float*)d_in[4];
  const float* w       = (const float*)d_in[5];
  const float* bias    = (const float*)d_in[6];
  float* out = (float*)d_out;
  const int n_nodes = in_sizes[2];

  __half* St = (__half*)d_ws;
  __half* P  = (__half*)((char*)d_ws + ST_BYTES);

  build_tables_kernel<<<N_REL, 256, 0, stream>>>(rel_emb, w, bias, St, P);
  const int nb = (n_nodes + 63) / 64;   // 782 blocks @ N=50000
  fuse_kernel<<<nb, 256, 0, stream>>>(out_nei, in_nei, target, feat, St, P,
                                      out, n_nodes);
}

// Round 13
// 20.757 us; speedup vs baseline: 6.8602x; 1.0247x over previous
//
#include <hip/hip_runtime.h>
#include <hip/hip_fp16.h>

#define N_REL 201   // NUM_RELS + 1 (PAD row 200 is all-zero)
#define N_TGT 200   // target_rels < 200
#define SEM 32      // SEM_DIM
#define KNEI 20     // K neighbors
#define PSTRIDE 40  // halfs per P row (80 B -> uniform spread over all 8 quad-groups)

typedef float floatx4 __attribute__((ext_vector_type(4)));

// Workspace: [0,80400) __half St[200][201]; [80400,+32160) __half P[402][40]
#define ST_BYTES 80400                 // 16-aligned (16*5025)
#define P_HALFS (2 * N_REL * PSTRIDE)  // 16080
#define P_U4 (P_HALFS * 2 / 16)        // 2010

#define EMB_STRIDE 68   // floats/row: 16B-aligned, dword-stride 17 (odd)
#define WL_STRIDE 132   // floats/row: 16B-aligned, dword-stride 33 (odd)

// ---------------------------------------------------------------------------
// Kernel 1 (vectorized): St[j][i] = emb[i]·emb[j] (fp16);
// P[dir*201+i][c] = emb[i]·W_dir_c + bias[c]/2 (fp16).
// ---------------------------------------------------------------------------
__global__ __launch_bounds__(256) void build_tables_kernel(
    const float* __restrict__ rel_emb,   // [201][64]
    const float* __restrict__ w,         // [32][128]
    const float* __restrict__ bias,      // [32]
    __half* __restrict__ St,             // [200][201] transposed
    __half* __restrict__ P)              // [402][PSTRIDE]
{
  __shared__ __align__(16) float embL[N_REL * EMB_STRIDE];
  __shared__ __align__(16) float wL[SEM * WL_STRIDE];
  const int t = threadIdx.x;
  for (int e = t; e < N_REL * 16; e += 256) {
    const int r = e >> 4, s = e & 15;
    *(float4*)&embL[r * EMB_STRIDE + s * 4] = ((const float4*)rel_emb)[e];
  }
  for (int e = t; e < SEM * 32; e += 256) {
    const int r = e >> 5, s = e & 31;
    *(float4*)&wL[r * WL_STRIDE + s * 4] = ((const float4*)w)[e];
  }
  __syncthreads();

  const int i = blockIdx.x;  // 0..200 (idx dimension)
  const float4* __restrict__ ri = (const float4*)&embL[i * EMB_STRIDE];
  for (int jj = t; jj < N_TGT; jj += 256) {
    const float4* __restrict__ rj = (const float4*)&embL[jj * EMB_STRIDE];
    float acc = 0.f;
#pragma unroll
    for (int d = 0; d < 16; ++d) {
      const float4 a = ri[d], b = rj[d];
      acc = fmaf(a.x, b.x, acc);
      acc = fmaf(a.y, b.y, acc);
      acc = fmaf(a.z, b.z, acc);
      acc = fmaf(a.w, b.w, acc);
    }
    St[jj * N_REL + i] = __float2half(acc);
  }
  if (t < 64) {
    const int hh = t >> 5, jj = t & 31;
    const float4* __restrict__ rw = (const float4*)&wL[jj * WL_STRIDE + hh * 64];
    float acc = 0.5f * bias[jj];
#pragma unroll
    for (int d = 0; d < 16; ++d) {
      const float4 a = ri[d], b = rw[d];
      acc = fmaf(a.x, b.x, acc);
      acc = fmaf(a.y, b.y, acc);
      acc = fmaf(a.z, b.z, acc);
      acc = fmaf(a.w, b.w, acc);
    }
    P[(hh * N_REL + i) * PSTRIDE + jj] = __float2half(acc);
  }
}

// ---------------------------------------------------------------------------
// Kernel 2: r7 structure (8 lanes/node, 256-thr, 1563 blocks, 24 waves/CU)
// + uint4 idx loads (2 VMEM instead of 5: lane q owns k in {4q..4q+3, 16+q})
// + PLAIN feat loads (keep lines L2-resident across graph replays)
// + NT stores only on out (reduce L2 dirty pressure).
// ---------------------------------------------------------------------------
__global__ __launch_bounds__(256, 4) void fuse_kernel(
    const int* __restrict__ out_nei, const int* __restrict__ in_nei,
    const int* __restrict__ target, const float* __restrict__ feat,
    const __half* __restrict__ St, const __half* __restrict__ Pg,
    float* __restrict__ out, int n_nodes)
{
  __shared__ __align__(16) __half P_l[P_HALFS];    // 32160 B
  const int t = threadIdx.x;
  const int gid = blockIdx.x * 256 + t;
  const int n = gid >> 3;
  const int sub = t & 7;
  const int dir = sub >> 2;   // 0 = out, 1 = in
  const int q = sub & 3;      // 8-dim slice / k-chunk
  const bool active = (n < n_nodes);
  const int* __restrict__ nei = dir ? in_nei : out_nei;

  // ---- phase 1: issue all input loads (latency hides under P staging) ----
  int tgt = 0, ex = 0;
  uint4 c4 = {0, 0, 0, 0};
  floatx4 f0, f1;
  if (active) {
    tgt = target[n];
    c4 = *(const uint4*)(nei + (size_t)n * KNEI + 4 * q);
    ex = nei[(size_t)n * KNEI + 16 + q];
    if (dir == 0) {
      const floatx4* fr = (const floatx4*)(feat + (size_t)n * SEM + q * 8);
      f0 = fr[0];           // plain loads: stay L2-resident across replays
      f1 = fr[1];
    }
  }

  // ---- phase 2: stage P into LDS ----
  {
    const uint4* p4 = (const uint4*)Pg;
    uint4* pl = (uint4*)P_l;
    for (int e = t; e < P_U4; e += 256) pl[e] = p4[e];
  }
  __syncthreads();
  if (!active) return;

  // ---- phase 3: S gathers (St row tgt, hot in L1/L2) ----
  const __half* __restrict__ srow = St + (size_t)tgt * N_REL;
  float ev[5];
  ev[0] = __half2float(srow[c4.x]);
  ev[1] = __half2float(srow[c4.y]);
  ev[2] = __half2float(srow[c4.z]);
  ev[3] = __half2float(srow[c4.w]);
  ev[4] = __half2float(srow[ex]);

  // ---- softmax with max-subtraction (self-neighbor scores ~ ||emb||^2) ----
  float mx = fmaxf(fmaxf(fmaxf(ev[0], ev[1]), fmaxf(ev[2], ev[3])), ev[4]);
  mx = fmaxf(mx, __shfl_xor(mx, 1, 64));
  mx = fmaxf(mx, __shfl_xor(mx, 2, 64));
  float e5[5], s = 0.f;
#pragma unroll
  for (int i = 0; i < 5; ++i) { e5[i] = __expf(ev[i] - mx); s += e5[i]; }
  s += __shfl_xor(s, 1, 64);
  s += __shfl_xor(s, 2, 64);
  const float inv = __fdividef(1.f, s);

  // ---- pack {idx | w_fp16}; all-gather within the dir quad ----
  const int ia[5] = {(int)c4.x, (int)c4.y, (int)c4.z, (int)c4.w, ex};
  unsigned int pk[20];
#pragma unroll
  for (int i = 0; i < 5; ++i) {
    const __half hw = __float2half(e5[i] * inv);
    pk[i] = ((unsigned int)ia[i] << 16) | (unsigned int)__half_as_ushort(hw);
  }
#pragma unroll
  for (int i = 0; i < 5; ++i) pk[5 + i] = __shfl_xor(pk[i], 1, 64);
#pragma unroll
  for (int i = 0; i < 10; ++i) pk[10 + i] = __shfl_xor(pk[i], 2, 64);

  // ---- aggregate 20 rows, own 8-dim slice (1 b128 per row, BW-floor) ----
  __half2 acc[4];
#pragma unroll
  for (int m = 0; m < 4; ++m) acc[m] = __float2half2_rn(0.f);
  const int dbase = dir * (N_REL * PSTRIDE) + q * 8;
#pragma unroll
  for (int i = 0; i < 20; ++i) {
    const int idx = (int)(pk[i] >> 16);
    const unsigned int lo = pk[i] & 0xFFFFu;
    const unsigned int dd = lo | (lo << 16);
    const __half2 a2 = *(const __half2*)&dd;
    const uint4 qv = *(const uint4*)&P_l[dbase + idx * PSTRIDE];
    acc[0] = __hfma2(a2, *(const __half2*)&qv.x, acc[0]);
    acc[1] = __hfma2(a2, *(const __half2*)&qv.y, acc[1]);
    acc[2] = __hfma2(a2, *(const __half2*)&qv.z, acc[2]);
    acc[3] = __hfma2(a2, *(const __half2*)&qv.w, acc[3]);
  }

  // ---- combine directions: partner lane = lane ^ 4 ----
#pragma unroll
  for (int m = 0; m < 4; ++m) {
    const unsigned int u = *(const unsigned int*)&acc[m];
    const unsigned int v = __shfl_xor(u, 4, 64);
    acc[m] = __hadd2(acc[m], *(const __half2*)&v);
  }

  // ---- write: lanes 0-3 -> feat slice, lanes 4-7 -> sigmoid slice (NT) ----
  float* orow = out + (size_t)n * 64 + sub * 8;
  if (dir == 0) {
    __builtin_nontemporal_store(f0, (floatx4*)orow);
    __builtin_nontemporal_store(f1, (floatx4*)orow + 1);
  } else {
    float tv[8];
#pragma unroll
    for (int m = 0; m < 4; ++m) {
      tv[2 * m]     = __low2float(acc[m]);
      tv[2 * m + 1] = __high2float(acc[m]);
    }
    floatx4 s0, s1;
    s0.x = __fdividef(1.f, 1.f + __expf(-tv[0]));
    s0.y = __fdividef(1.f, 1.f + __expf(-tv[1]));
    s0.z = __fdividef(1.f, 1.f + __expf(-tv[2]));
    s0.w = __fdividef(1.f, 1.f + __expf(-tv[3]));
    s1.x = __fdividef(1.f, 1.f + __expf(-tv[4]));
    s1.y = __fdividef(1.f, 1.f + __expf(-tv[5]));
    s1.z = __fdividef(1.f, 1.f + __expf(-tv[6]));
    s1.w = __fdividef(1.f, 1.f + __expf(-tv[7]));
    __builtin_nontemporal_store(s0, (floatx4*)orow);
    __builtin_nontemporal_store(s1, (floatx4*)orow + 1);
  }
}

extern "C" void kernel_launch(void* const* d_in, const int* in_sizes, int n_in,
                              void* d_out, int out_size, void* d_ws, size_t ws_size,
                              hipStream_t stream) {
  const int* out_nei   = (const int*)d_in[0];
  const int* in_nei    = (const int*)d_in[1];
  const int* target    = (const int*)d_in[2];
  const float* feat    = (const float*)d_in[3];
  const float* rel_emb = (const float*)d_in[4];
  const float* w       = (const float*)d_in[5];
  const float* bias    = (const float*)d_in[6];
  float* out = (float*)d_out;
  const int n_nodes = in_sizes[2];

  __half* St = (__half*)d_ws;
  __half* P  = (__half*)((char*)d_ws + ST_BYTES);

  build_tables_kernel<<<N_REL, 256, 0, stream>>>(rel_emb, w, bias, St, P);
  const int total_threads = n_nodes * 8;
  const int nb = (total_threads + 255) / 256;   // 1563 blocks @ N=50000
  fuse_kernel<<<nb, 256, 0, stream>>>(out_nei, in_nei, target, feat, St, P,
                                      out, n_nodes);
}